// Round 4
// baseline (438.073 us; speedup 1.0000x reference)
//
#include <hip/hip_runtime.h>
#include <math.h>

// VQ-AE forward, single fused kernel with SOFTWARE grid barriers (R4).
// R3's hipLaunchCooperativeKernel silently failed under graph capture (out=0);
// R4 uses a plain launch + monotonic device-scope atomic barrier. Co-residency
// by construction: LDS 58880B -> 2 blocks/CU hard cap, launch_bounds(256,2) ->
// VGPR<=256, grid 512 = 2 x 256 CUs exactly.
// Structure: P1 enc1 (h1 in regs) -> gsync -> P2 BN1+enc2(split-bf16)+quant+dec1
// (h2 in regs) -> gsync -> P3 BN2+dec2 with direct (X_-X)^2 epilogue (X re-read
// L3-resident). All intermediate HBM arrays (h1/h2b/Yb) eliminated.
// z-path accuracy-critical: h1 fp32 in regs, z via split-bf16 MFMA (3 products),
// exact fp32 selected-distance. Post-topics path single bf16.
//
// ws: acc[1024] f32 | cbb[1024*32] bf16 | cn_g[1024] f32
// acc: [0..127] sum1, [128..255] sumsq1, [256..383] sum2, [384..511] sumsq2,
//      [512] min-dist sum, [513] sum((X_-X)^2), [520] barrier counter (int)

typedef __attribute__((ext_vector_type(8))) short bf8;
typedef __attribute__((ext_vector_type(4))) float f4a;

__device__ __forceinline__ unsigned short f2bf(float f) {
    unsigned u = __float_as_uint(f);
    u += 0x7fffu + ((u >> 16) & 1u);   // RNE
    return (unsigned short)(u >> 16);
}
__device__ __forceinline__ float bf2f(unsigned short h) {
    return __uint_as_float((unsigned)h << 16);
}
__device__ __forceinline__ unsigned pack2(float a, float b) {
    return (unsigned)f2bf(a) | ((unsigned)f2bf(b) << 16);
}

// Monotonic software grid barrier. All blocks co-resident by construction.
// acc_g data crossing the barrier is written ONLY via device-scope atomicAdd;
// readers after the barrier use agent-scope atomic loads (XCD-L2-coherent).
__device__ __forceinline__ void gsync(int* cnt, int goal) {
    __syncthreads();
    if (threadIdx.x == 0) {
        __threadfence();
        __hip_atomic_fetch_add(cnt, 1, __ATOMIC_RELEASE, __HIP_MEMORY_SCOPE_AGENT);
        while (__hip_atomic_load(cnt, __ATOMIC_ACQUIRE, __HIP_MEMORY_SCOPE_AGENT) < goal)
            __builtin_amdgcn_s_sleep(2);
    }
    __syncthreads();
}
__device__ __forceinline__ float aload(const float* p) {
    return __hip_atomic_load(p, __ATOMIC_RELAXED, __HIP_MEMORY_SCOPE_AGENT);
}

// ======== K0: zero acc + codebook -> bf16 + fp32 norms ========
__global__ __launch_bounds__(256) void k_prep(const float* __restrict__ cb,
                                              float* __restrict__ acc,
                                              unsigned short* __restrict__ cbb,
                                              float* __restrict__ cn_g) {
    const int b = blockIdx.x, t = threadIdx.x;
    if (b < 4) {
        const int cw = (b << 8) + t;
        const float* p = cb + (size_t)cw * 32;
        unsigned out[16];
        float n = 0.f;
#pragma unroll
        for (int i = 0; i < 8; ++i) {
            float4 v = *(const float4*)(p + (i << 2));
            n = fmaf(v.x, v.x, n); n = fmaf(v.y, v.y, n);
            n = fmaf(v.z, v.z, n); n = fmaf(v.w, v.w, n);
            out[2 * i]     = pack2(v.x, v.y);
            out[2 * i + 1] = pack2(v.z, v.w);
        }
#pragma unroll
        for (int i = 0; i < 4; ++i)
            *(uint4*)(cbb + (size_t)cw * 32 + (i << 3)) =
                make_uint4(out[4 * i], out[4 * i + 1], out[4 * i + 2], out[4 * i + 3]);
        cn_g[cw] = n;
    } else {
        for (int i = t; i < 1024; i += 256) acc[i] = 0.f;
    }
}

// ======== K1: fused pipeline (plain launch, 512 x 256, 2 blocks/CU) ========
// LDS pool 58880 B, phase overlays (all uses separated by barriers):
//  [0,18432)      P1 As / P2a Ash / P2b cs[0,20480) / P2c W1dT / P3 Ad[0,34816)
//  [18432,36864)  P1 Bs / P2a Asl / P2c Qs@10240 / (P3 Ad tail)
//  [36864,40960)  P1 sred f32[1024]
//  [36864,41472)  P2a B2h ; [41472,46080) B2l
//  [20480,21504)  P2b cn f32[256] ; [20480,24576) P2c sstat2 f32[1024]
//  [34816,45056)  P3 Bsd (w2d chunk [128][40])
//  [46080,56320)  zs bf16 z [128][40] (P2a -> P2b)
//  [56320,57344)  scl/shf f32[128] each | [57344,57856) topicsL | [57856,58880) red
__global__ __launch_bounds__(256, 2) void k_fused(
    const float* __restrict__ X,
    const float* __restrict__ w1,    // enc_w1 [512][128]
    const float* __restrict__ b1,    // enc_b1 [128]
    const float* __restrict__ g1,
    const float* __restrict__ be1,
    const float* __restrict__ w2e,   // enc_w2 [128][32]
    const float* __restrict__ b2e,   // enc_b2 [32]
    const float* __restrict__ w1d,   // dec_w1 [32][128]
    const float* __restrict__ b1d,   // dec_b1 [128]
    const float* __restrict__ g2,
    const float* __restrict__ be2,
    const float* __restrict__ w2d,   // dec_w2 [128][512]
    const float* __restrict__ b2d,   // dec_b2 [512]
    const float* __restrict__ cb,    // codebook fp32 [1024][32]
    const unsigned short* __restrict__ cbb,
    const float* __restrict__ cn_g,
    float* __restrict__ acc_g)
{
    __shared__ __align__(16) char pool[58880];
    unsigned short* As   = (unsigned short*)pool;               // P1 A / P2a Ash
    unsigned short* Bs   = (unsigned short*)(pool + 18432);     // P1 B / P2a Asl
    float*          sred = (float*)(pool + 36864);
    unsigned short* B2h  = (unsigned short*)(pool + 36864);
    unsigned short* B2l  = (unsigned short*)(pool + 41472);
    unsigned short* zs   = (unsigned short*)(pool + 46080);
    unsigned short* cs   = (unsigned short*)pool;
    float*          cn   = (float*)(pool + 20480);
    unsigned short* W1dT = (unsigned short*)pool;
    unsigned short* Qs   = (unsigned short*)(pool + 10240);
    float*          sst2 = (float*)(pool + 20480);
    unsigned short* Ad   = (unsigned short*)pool;               // P3 [128][136]
    unsigned short* Bsd  = (unsigned short*)(pool + 34816);     // P3 [128][40]
    float* scl     = (float*)(pool + 56320);
    float* shf     = (float*)(pool + 56832);
    int*   topicsL = (int*)(pool + 57344);
    float* red     = (float*)(pool + 57856);

    const int t = threadIdx.x;
    const int w = t >> 6, lane = t & 63, quad = lane >> 4, lcol = lane & 15;
    const int row0 = blockIdx.x << 7;
    int* bar = (int*)(acc_g + 520);

    // ================= P1: h1 = X@w1 (regs) + BN1 column stats =================
    f4a acc[2][8];
#pragma unroll
    for (int i = 0; i < 2; ++i)
#pragma unroll
        for (int j = 0; j < 8; ++j) acc[i][j] = (f4a){0.f, 0.f, 0.f, 0.f};

    const int arb = t >> 4;               // A-row sub-index
    const int akq = (t & 15) << 2;        // A k-quad
    const int bn = t & 127, bkg = t >> 7; // w1 gather coords
    float4 xa[8], wb[8];
    // prologue: load chunk 0 (reg-staging)
#pragma unroll
    for (int i = 0; i < 8; ++i) {
        xa[i] = *(const float4*)(X + (size_t)(row0 + (i << 4) + arb) * 512 + akq);
        const int k = (bkg << 5) + (i << 2);
        const float* p = w1 + (size_t)k * 128 + bn;
        wb[i] = make_float4(p[0], p[128], p[256], p[384]);
    }
    for (int c = 0; c < 8; ++c) {
        __syncthreads();
        // write staged regs -> LDS (fp32 -> bf16)
#pragma unroll
        for (int i = 0; i < 8; ++i) {
            const int r = (i << 4) + arb;
            *(uint2*)&As[r * 72 + akq] =
                make_uint2(pack2(xa[i].x, xa[i].y), pack2(xa[i].z, xa[i].w));
        }
#pragma unroll
        for (int i = 0; i < 8; ++i) {
            const int k = (bkg << 5) + (i << 2);
            *(uint2*)&Bs[bn * 72 + k] =
                make_uint2(pack2(wb[i].x, wb[i].y), pack2(wb[i].z, wb[i].w));
        }
        __syncthreads();
        if (c < 7) {   // issue next chunk's loads before MFMA (latency hidden)
            const int k0n = (c + 1) << 6;
#pragma unroll
            for (int i = 0; i < 8; ++i) {
                xa[i] = *(const float4*)(X + (size_t)(row0 + (i << 4) + arb) * 512 + k0n + akq);
                const int k = (bkg << 5) + (i << 2);
                const float* p = w1 + (size_t)(k0n + k) * 128 + bn;
                wb[i] = make_float4(p[0], p[128], p[256], p[384]);
            }
        }
#pragma unroll
        for (int ks = 0; ks < 2; ++ks) {
            const bf8 a0 = *(const bf8*)&As[(w * 32 + lcol) * 72 + (ks << 5) + (quad << 3)];
            const bf8 a1 = *(const bf8*)&As[(w * 32 + 16 + lcol) * 72 + (ks << 5) + (quad << 3)];
#pragma unroll
            for (int nt = 0; nt < 8; ++nt) {
                const bf8 bb = *(const bf8*)&Bs[(nt * 16 + lcol) * 72 + (ks << 5) + (quad << 3)];
                acc[0][nt] = __builtin_amdgcn_mfma_f32_16x16x32_bf16(a0, bb, acc[0][nt], 0, 0, 0);
                acc[1][nt] = __builtin_amdgcn_mfma_f32_16x16x32_bf16(a1, bb, acc[1][nt], 0, 0, 0);
            }
        }
    }
    // column stats of h1 = acc + b1 (h1 never leaves registers)
#pragma unroll
    for (int nt = 0; nt < 8; ++nt) {
        const int gc = (nt << 4) + lcol;
        const float bias = b1[gc];
        float s = 0.f, ss = 0.f;
#pragma unroll
        for (int mt = 0; mt < 2; ++mt)
#pragma unroll
            for (int r = 0; r < 4; ++r) {
                float v = acc[mt][nt][r] + bias;
                s += v;
                ss = fmaf(v, v, ss);
            }
        s += __shfl_xor(s, 16);  s += __shfl_xor(s, 32);
        ss += __shfl_xor(ss, 16); ss += __shfl_xor(ss, 32);
        if (quad == 0) { sred[w * 128 + gc] = s; sred[512 + w * 128 + gc] = ss; }
    }
    __syncthreads();
    if (t < 128) {
        atomicAdd(&acc_g[t], sred[t] + sred[128 + t] + sred[256 + t] + sred[384 + t]);
        atomicAdd(&acc_g[128 + t], sred[512 + t] + sred[640 + t] + sred[768 + t] + sred[896 + t]);
    }
    gsync(bar, 512);

    // ================= P2: BN1 -> z (split-bf16) -> quant -> dec1 =================
    if (t < 128) {
        float mu = aload(&acc_g[t]) * (1.f / 65536.f);
        float var = fmaf(-mu, mu, aload(&acc_g[128 + t]) * (1.f / 65536.f));
        float s = g1[t] * rsqrtf(var + 1e-5f);
        scl[t] = s;
        shf[t] = fmaf(-mu, s, be1[t]);
    }
    __syncthreads();

    f4a zacc[2][2];
#pragma unroll
    for (int i = 0; i < 2; ++i)
#pragma unroll
        for (int j = 0; j < 2; ++j) zacc[i][j] = (f4a){0.f, 0.f, 0.f, 0.f};

    // K=128 processed in two clean 64-wide chunks
#pragma unroll
    for (int h = 0; h < 2; ++h) {
        // convert own h1 regs (cols nt in [4h,4h+4)) -> hi (As) / lo (Bs)
#pragma unroll
        for (int nt4 = 0; nt4 < 4; ++nt4) {
            const int nt = (h << 2) + nt4;
            const int gc = (nt << 4) + lcol;
            const float sclv = scl[gc], shfv = shf[gc], bias = b1[gc];
            const int kk = (nt4 << 4) + lcol;
#pragma unroll
            for (int mt = 0; mt < 2; ++mt)
#pragma unroll
                for (int r = 0; r < 4; ++r) {
                    const int row = w * 32 + mt * 16 + (quad << 2) + r;
                    float v = acc[mt][nt][r] + bias;
                    float a = fmaxf(fmaf(v, sclv, shfv), 0.f);
                    unsigned short hi = f2bf(a);
                    As[row * 72 + kk] = hi;
                    Bs[row * 72 + kk] = f2bf(a - bf2f(hi));
                }
        }
        // stage w2e half-K hi/lo: [32 n][64 k']
#pragma unroll
        for (int i = 0; i < 8; ++i) {
            const int idx = (i << 8) + t;
            const int n = idx & 31, kk2 = idx >> 5;   // kk2 0..63
            const float f = w2e[(size_t)((h << 6) + kk2) * 32 + n];
            unsigned short hi = f2bf(f);
            B2h[n * 72 + kk2] = hi;
            B2l[n * 72 + kk2] = f2bf(f - bf2f(hi));
        }
        __syncthreads();
#pragma unroll
        for (int kc = 0; kc < 2; ++kc) {
            const int ko = (kc << 5) + (quad << 3);
            const bf8 ah0 = *(const bf8*)&As[(w * 32 + lcol) * 72 + ko];
            const bf8 ah1 = *(const bf8*)&As[(w * 32 + 16 + lcol) * 72 + ko];
            const bf8 al0 = *(const bf8*)&Bs[(w * 32 + lcol) * 72 + ko];
            const bf8 al1 = *(const bf8*)&Bs[(w * 32 + 16 + lcol) * 72 + ko];
            const bf8 bh0 = *(const bf8*)&B2h[lcol * 72 + ko];
            const bf8 bh1 = *(const bf8*)&B2h[(16 + lcol) * 72 + ko];
            const bf8 bl0 = *(const bf8*)&B2l[lcol * 72 + ko];
            const bf8 bl1 = *(const bf8*)&B2l[(16 + lcol) * 72 + ko];
            zacc[0][0] = __builtin_amdgcn_mfma_f32_16x16x32_bf16(ah0, bh0, zacc[0][0], 0, 0, 0);
            zacc[0][0] = __builtin_amdgcn_mfma_f32_16x16x32_bf16(al0, bh0, zacc[0][0], 0, 0, 0);
            zacc[0][0] = __builtin_amdgcn_mfma_f32_16x16x32_bf16(ah0, bl0, zacc[0][0], 0, 0, 0);
            zacc[0][1] = __builtin_amdgcn_mfma_f32_16x16x32_bf16(ah0, bh1, zacc[0][1], 0, 0, 0);
            zacc[0][1] = __builtin_amdgcn_mfma_f32_16x16x32_bf16(al0, bh1, zacc[0][1], 0, 0, 0);
            zacc[0][1] = __builtin_amdgcn_mfma_f32_16x16x32_bf16(ah0, bl1, zacc[0][1], 0, 0, 0);
            zacc[1][0] = __builtin_amdgcn_mfma_f32_16x16x32_bf16(ah1, bh0, zacc[1][0], 0, 0, 0);
            zacc[1][0] = __builtin_amdgcn_mfma_f32_16x16x32_bf16(al1, bh0, zacc[1][0], 0, 0, 0);
            zacc[1][0] = __builtin_amdgcn_mfma_f32_16x16x32_bf16(ah1, bl0, zacc[1][0], 0, 0, 0);
            zacc[1][1] = __builtin_amdgcn_mfma_f32_16x16x32_bf16(ah1, bh1, zacc[1][1], 0, 0, 0);
            zacc[1][1] = __builtin_amdgcn_mfma_f32_16x16x32_bf16(al1, bh1, zacc[1][1], 0, 0, 0);
            zacc[1][1] = __builtin_amdgcn_mfma_f32_16x16x32_bf16(ah1, bl1, zacc[1][1], 0, 0, 0);
        }
        __syncthreads();
    }
    // bias; fp32 z in regs; bf16 z -> zs (A-layout)
    const float b2lo = b2e[lcol], b2hi = b2e[16 + lcol];
    float zf0[2][4], zf1[2][4];
#pragma unroll
    for (int mt = 0; mt < 2; ++mt)
#pragma unroll
        for (int r = 0; r < 4; ++r) {
            float v0 = zacc[mt][0][r] + b2lo;
            float v1 = zacc[mt][1][r] + b2hi;
            zf0[mt][r] = v0;
            zf1[mt][r] = v1;
            int row = w * 32 + mt * 16 + (quad << 2) + r;
            zs[row * 40 + lcol] = f2bf(v0);
            zs[row * 40 + 16 + lcol] = f2bf(v1);
        }
    __syncthreads();

    // --- quant sweep (bf16 proxy argmin) ---
    bf8 af[2];
    af[0] = *(const bf8*)&zs[(w * 32 + lcol) * 40 + (quad << 3)];
    af[1] = *(const bf8*)&zs[(w * 32 + 16 + lcol) * 40 + (quad << 3)];
    float best[2][4];
    int bidx[2][4];
#pragma unroll
    for (int mt = 0; mt < 2; ++mt)
#pragma unroll
        for (int r = 0; r < 4; ++r) { best[mt][r] = 3.4e38f; bidx[mt][r] = 0; }
    const f4a zero4 = {0.f, 0.f, 0.f, 0.f};

    for (int cp = 0; cp < 4; ++cp) {
        if (cp) __syncthreads();
#pragma unroll
        for (int i = 0; i < 4; ++i) {
            int idx = (i << 8) + t;
            int r = idx >> 2, kq = (idx & 3) << 3;
            *(uint4*)&cs[r * 40 + kq] = *(const uint4*)(cbb + (size_t)((cp << 8) + r) * 32 + kq);
        }
        cn[t] = cn_g[(cp << 8) + t];
        __syncthreads();
        bf8 bb = *(const bf8*)&cs[lcol * 40 + (quad << 3)];
        float cnv = cn[lcol];
        for (int ch = 0; ch < 16; ++ch) {
            const int nn = ((ch + 1) & 15) << 4;
            const bf8 bb_n = *(const bf8*)&cs[(nn + lcol) * 40 + (quad << 3)];
            const float cn_n = cn[nn + lcol];
            const int cidx = (cp << 8) + (ch << 4) + lcol;
#pragma unroll
            for (int mt = 0; mt < 2; ++mt) {
                f4a a = __builtin_amdgcn_mfma_f32_16x16x32_bf16(af[mt], bb, zero4, 0, 0, 0);
#pragma unroll
                for (int r = 0; r < 4; ++r) {
                    float d = fmaf(-2.f, a[r], cnv);
                    if (d < best[mt][r]) { best[mt][r] = d; bidx[mt][r] = cidx; }
                }
            }
            bb = bb_n; cnv = cn_n;
        }
    }
#pragma unroll
    for (int off = 1; off < 16; off <<= 1) {
#pragma unroll
        for (int mt = 0; mt < 2; ++mt)
#pragma unroll
            for (int r = 0; r < 4; ++r) {
                float ob = __shfl_xor(best[mt][r], off);
                int oi = __shfl_xor(bidx[mt][r], off);
                if (ob < best[mt][r] || (ob == best[mt][r] && oi < bidx[mt][r])) {
                    best[mt][r] = ob; bidx[mt][r] = oi;
                }
            }
    }
    // exact fp32 distance of selected codeword (register z, fp32 cb)
    float lsum = 0.f;
#pragma unroll
    for (int mt = 0; mt < 2; ++mt)
#pragma unroll
        for (int r = 0; r < 4; ++r) {
            const int rowl = w * 32 + mt * 16 + (quad << 2) + r;
            const int ti = bidx[mt][r];
            const float* cp_ = cb + (size_t)ti * 32;
            float d0 = zf0[mt][r] - cp_[lcol];
            float d1 = zf1[mt][r] - cp_[16 + lcol];
            float p = fmaf(d0, d0, d1 * d1);
            p += __shfl_xor(p, 1); p += __shfl_xor(p, 2);
            p += __shfl_xor(p, 4); p += __shfl_xor(p, 8);
            if (lcol == 0) {
                topicsL[rowl] = ti;
                lsum += p;
            }
        }
    red[t] = lsum;
    __syncthreads();
    for (int s = 128; s > 0; s >>= 1) {
        if (t < s) red[t] += red[t + s];
        __syncthreads();
    }
    if (t == 0) atomicAdd(acc_g + 512, red[0]);

    // --- dec1: h2 = q@w1d + b1d (regs) + BN2 column stats ---
#pragma unroll
    for (int i = 0; i < 8; ++i) {
        int idx = (i << 8) + t;
        int n = idx & 127, kp = idx >> 7;
        unsigned v = pack2(w1d[(size_t)(2 * kp) * 128 + n],
                           w1d[(size_t)(2 * kp + 1) * 128 + n]);
        *(unsigned*)&W1dT[n * 40 + (kp << 1)] = v;
    }
#pragma unroll
    for (int i = 0; i < 2; ++i) {
        int idx = (i << 8) + t;
        int r = idx >> 2, p = idx & 3;
        *(uint4*)&Qs[r * 40 + (p << 3)] =
            *(const uint4*)(cbb + (size_t)topicsL[r] * 32 + (p << 3));
    }
    __syncthreads();
    f4a dacc[2][8];
#pragma unroll
    for (int i = 0; i < 2; ++i)
#pragma unroll
        for (int j = 0; j < 8; ++j) dacc[i][j] = (f4a){0.f, 0.f, 0.f, 0.f};
    const bf8 da0 = *(const bf8*)&Qs[(w * 32 + lcol) * 40 + (quad << 3)];
    const bf8 da1 = *(const bf8*)&Qs[(w * 32 + 16 + lcol) * 40 + (quad << 3)];
#pragma unroll
    for (int nt = 0; nt < 8; ++nt) {
        const bf8 bb = *(const bf8*)&W1dT[(nt * 16 + lcol) * 40 + (quad << 3)];
        dacc[0][nt] = __builtin_amdgcn_mfma_f32_16x16x32_bf16(da0, bb, dacc[0][nt], 0, 0, 0);
        dacc[1][nt] = __builtin_amdgcn_mfma_f32_16x16x32_bf16(da1, bb, dacc[1][nt], 0, 0, 0);
    }
#pragma unroll
    for (int nt = 0; nt < 8; ++nt) {
        const int gc = (nt << 4) + lcol;
        const float bias = b1d[gc];
        float s = 0.f, ss = 0.f;
#pragma unroll
        for (int mt = 0; mt < 2; ++mt)
#pragma unroll
            for (int r = 0; r < 4; ++r) {
                float v = dacc[mt][nt][r] + bias;
                dacc[mt][nt][r] = v;   // keep h2 (with bias) in regs
                s += v;
                ss = fmaf(v, v, ss);
            }
        s += __shfl_xor(s, 16);  s += __shfl_xor(s, 32);
        ss += __shfl_xor(ss, 16); ss += __shfl_xor(ss, 32);
        if (quad == 0) { sst2[w * 128 + gc] = s; sst2[512 + w * 128 + gc] = ss; }
    }
    __syncthreads();
    if (t < 128) {
        atomicAdd(&acc_g[256 + t], sst2[t] + sst2[128 + t] + sst2[256 + t] + sst2[384 + t]);
        atomicAdd(&acc_g[384 + t], sst2[512 + t] + sst2[640 + t] + sst2[768 + t] + sst2[896 + t]);
    }
    gsync(bar, 1024);

    // ================= P3: BN2 -> dec2 -> sum((X_-X)^2) =================
    if (t < 128) {
        float mu = aload(&acc_g[256 + t]) * (1.f / 65536.f);
        float var = fmaf(-mu, mu, aload(&acc_g[384 + t]) * (1.f / 65536.f));
        float s = g2[t] * rsqrtf(var + 1e-5f);
        scl[t] = s;
        shf[t] = fmaf(-mu, s, be2[t]);
    }
    __syncthreads();
    // H2r = relu(bn2(h2)) -> Ad [128][136] bf16
#pragma unroll
    for (int nt = 0; nt < 8; ++nt) {
        const int gc = (nt << 4) + lcol;
        const float sclv = scl[gc], shfv = shf[gc];
#pragma unroll
        for (int mt = 0; mt < 2; ++mt)
#pragma unroll
            for (int r = 0; r < 4; ++r) {
                const int row = w * 32 + mt * 16 + (quad << 2) + r;
                float hr = fmaxf(fmaf(dacc[mt][nt][r], sclv, shfv), 0.f);
                Ad[row * 136 + gc] = f2bf(hr);
            }
    }
    __syncthreads();
    float l2 = 0.f;
    for (int nc = 0; nc < 4; ++nc) {      // 4 x 128 output cols
        f4a acc2[2][8];
#pragma unroll
        for (int i = 0; i < 2; ++i)
#pragma unroll
            for (int j = 0; j < 8; ++j) acc2[i][j] = (f4a){0.f, 0.f, 0.f, 0.f};
        for (int kc = 0; kc < 4; ++kc) {  // 4 x 32 K
            if (nc | kc) __syncthreads();
            {   // Bsd <- w2d[kc-chunk][nc-chunk] bf16 (L2-resident)
                const int nl = t & 127, kh = t >> 7;
#pragma unroll
                for (int j = 0; j < 8; ++j) {
                    const int kk = (kh << 4) + (j << 1);
                    const float f0 = w2d[(size_t)((kc << 5) + kk) * 512 + (nc << 7) + nl];
                    const float f1 = w2d[(size_t)((kc << 5) + kk + 1) * 512 + (nc << 7) + nl];
                    *(unsigned*)&Bsd[nl * 40 + kk] = pack2(f0, f1);
                }
            }
            __syncthreads();
            const bf8 af0 = *(const bf8*)&Ad[(w * 32 + lcol) * 136 + (kc << 5) + (quad << 3)];
            const bf8 af1 = *(const bf8*)&Ad[(w * 32 + 16 + lcol) * 136 + (kc << 5) + (quad << 3)];
#pragma unroll
            for (int nt = 0; nt < 8; ++nt) {
                const bf8 bb = *(const bf8*)&Bsd[(nt * 16 + lcol) * 40 + (quad << 3)];
                acc2[0][nt] = __builtin_amdgcn_mfma_f32_16x16x32_bf16(af0, bb, acc2[0][nt], 0, 0, 0);
                acc2[1][nt] = __builtin_amdgcn_mfma_f32_16x16x32_bf16(af1, bb, acc2[1][nt], 0, 0, 0);
            }
        }
        // epilogue: direct (X_ - X)^2, X re-read L3-resident
#pragma unroll
        for (int nt = 0; nt < 8; ++nt) {
            const int gcol = (nc << 7) + (nt << 4) + lcol;
            const float bias = b2d[gcol];
#pragma unroll
            for (int mt = 0; mt < 2; ++mt) {
                const int rbase = row0 + w * 32 + mt * 16 + (quad << 2);
#pragma unroll
                for (int r = 0; r < 4; ++r) {
                    const float val = acc2[mt][nt][r] + bias;
                    const float d = val - X[(size_t)(rbase + r) * 512 + gcol];
                    l2 = fmaf(d, d, l2);
                }
            }
        }
    }
    red[t] = l2;
    __syncthreads();
    for (int s = 128; s > 0; s >>= 1) {
        if (t < s) red[t] += red[t + s];
        __syncthreads();
    }
    if (t == 0) atomicAdd(acc_g + 513, red[0]);
}

// ======== K2: out = 2*z_loss + sqrt(sum((X_-X)^2)) ========
__global__ void k_final(const float* __restrict__ acc, float* __restrict__ out) {
    if (threadIdx.x == 0)
        out[0] = 2.f * acc[512] + sqrtf(acc[513]);
}

extern "C" void kernel_launch(void* const* d_in, const int* in_sizes, int n_in,
                              void* d_out, int out_size, void* d_ws, size_t ws_size,
                              hipStream_t stream) {
    const float* X       = (const float*)d_in[0];
    const float* enc_w1  = (const float*)d_in[1];
    const float* enc_b1  = (const float*)d_in[2];
    const float* enc_g1  = (const float*)d_in[3];
    const float* enc_be1 = (const float*)d_in[4];
    const float* enc_w2  = (const float*)d_in[5];
    const float* enc_b2  = (const float*)d_in[6];
    const float* dec_w1  = (const float*)d_in[7];
    const float* dec_b1  = (const float*)d_in[8];
    const float* dec_g1  = (const float*)d_in[9];
    const float* dec_be1 = (const float*)d_in[10];
    const float* dec_w2  = (const float*)d_in[11];
    const float* dec_b2  = (const float*)d_in[12];
    const float* cb      = (const float*)d_in[13];
    float* out = (float*)d_out;

    float* acc = (float*)d_ws;                               // 1024 f32 (incl. barrier)
    unsigned short* cbb = (unsigned short*)(acc + 1024);     // 1024*32 bf16
    float* cn_g = (float*)(cbb + 1024 * 32);                 // 1024 f32

    k_prep<<<5, 256, 0, stream>>>(cb, acc, cbb, cn_g);
    k_fused<<<512, 256, 0, stream>>>(X, enc_w1, enc_b1, enc_g1, enc_be1,
                                     enc_w2, enc_b2, dec_w1, dec_b1,
                                     dec_g1, dec_be1, dec_w2, dec_b2,
                                     cb, cbb, cn_g, acc);
    k_final<<<1, 64, 0, stream>>>(acc, out);
}